// Round 1
// baseline (304.890 us; speedup 1.0000x reference)
//
#include <hip/hip_runtime.h>
#include <math.h>

#define HDIM 768
#define BDIM 256
#define INDIM 64
#define NLAYERS 4
#define PDIM 8
#define KS 12      // k-splits
#define KLEN 64    // k per split
#define CHK 16     // k chunk staged in LDS
#define TR 128     // rows per block tile
#define TC 64      // cols per block tile

__device__ __forceinline__ float sigmoidf_(float x) { return 1.f / (1.f + expf(-x)); }
__device__ __forceinline__ float geluf_(float x) { return 0.5f * x * (1.f + erff(x * 0.70710678118654752f)); }

// ---------------------------------------------------------------------------
// Kernel 0: h = x @ w_in + b_in, then LN(layer 0) -> hn.  One block per row.
// ---------------------------------------------------------------------------
__global__ __launch_bounds__(256) void input_ln_k(
    const float* __restrict__ x, const float* __restrict__ w_in,
    const float* __restrict__ b_in,
    const float* __restrict__ lng, const float* __restrict__ lnb,
    float* __restrict__ h, float* __restrict__ hn)
{
    const int b = blockIdx.x;
    const int t = threadIdx.x;
    __shared__ float xs[INDIM];
    __shared__ float rbuf[8];
    if (t < INDIM) xs[t] = x[b * INDIM + t];
    __syncthreads();

    float acc0 = b_in[t], acc1 = b_in[t + 256], acc2 = b_in[t + 512];
#pragma unroll 8
    for (int i = 0; i < INDIM; ++i) {
        const float xv = xs[i];
        acc0 = fmaf(xv, w_in[i * HDIM + t], acc0);
        acc1 = fmaf(xv, w_in[i * HDIM + t + 256], acc1);
        acc2 = fmaf(xv, w_in[i * HDIM + t + 512], acc2);
    }
    h[(size_t)b * HDIM + t] = acc0;
    h[(size_t)b * HDIM + t + 256] = acc1;
    h[(size_t)b * HDIM + t + 512] = acc2;

    float s = acc0 + acc1 + acc2;
    float q = acc0 * acc0 + acc1 * acc1 + acc2 * acc2;
#pragma unroll
    for (int off = 32; off > 0; off >>= 1) { s += __shfl_down(s, off); q += __shfl_down(q, off); }
    const int wid = t >> 6, lane = t & 63;
    if (lane == 0) { rbuf[wid] = s; rbuf[4 + wid] = q; }
    __syncthreads();
    s = rbuf[0] + rbuf[1] + rbuf[2] + rbuf[3];
    q = rbuf[4] + rbuf[5] + rbuf[6] + rbuf[7];
    const float mu = s * (1.f / HDIM);
    const float var = q * (1.f / HDIM) - mu * mu;
    const float rsig = rsqrtf(var + 1e-5f);

    hn[(size_t)b * HDIM + t]       = (acc0 - mu) * rsig * lng[t] + lnb[t];
    hn[(size_t)b * HDIM + t + 256] = (acc1 - mu) * rsig * lng[t + 256] + lnb[t + 256];
    hn[(size_t)b * HDIM + t + 512] = (acc2 - mu) * rsig * lng[t + 512] + lnb[t + 512];
}

// ---------------------------------------------------------------------------
// Kernel 1 (per layer): fused triple "matmul" partials over a k-split.
//   trop: max-plus (semiring), cls/gate: fp32 FMA.
// Block: 256 threads, tile TR(128) rows x TC(64) cols, thread: 8x4.
// Grid: (H/TC=12, B/TR=2, KS=12) = 288 blocks.
// ---------------------------------------------------------------------------
__global__ __launch_bounds__(256, 2) void layer_mm_k(
    const float* __restrict__ hn,
    const float* __restrict__ twp,   // trop_w[l] : [o][i]
    const float* __restrict__ cwp,   // cls_w[l]  : [i][o]
    const float* __restrict__ gwp,   // gate_w[l] : [i][o]
    float* __restrict__ p_trop, float* __restrict__ p_cls, float* __restrict__ p_gate)
{
    __shared__ float hn_s[CHK][TR + 4];  // [k][row], stride 132 floats (16B aligned)
    __shared__ float wt_s[CHK][TC + 4];  // [k][col], stride 68
    __shared__ float wc_s[CHK][TC + 4];
    __shared__ float wg_s[CHK][TC + 4];

    const int tid = threadIdx.x;
    const int col0 = blockIdx.x * TC;
    const int row0 = blockIdx.y * TR;
    const int k0 = blockIdx.z * KLEN;

    const int tx = tid & 15;   // col group
    const int ty = tid >> 4;   // row group (0..15)
    const int r0 = ty * 8;
    const int c0 = tx * 4;

    // loader indices
    const int lr = tid >> 2;          // 0..63
    const int lk = (tid & 3) * 4;     // 0,4,8,12
    const int ck = tid >> 4;          // 0..15 (k row for cls/gate tile)
    const int co = (tid & 15) * 4;

    float t_acc[8][4], c_acc[8][4], g_acc[8][4];
#pragma unroll
    for (int i = 0; i < 8; ++i)
#pragma unroll
        for (int j = 0; j < 4; ++j) { t_acc[i][j] = -1e30f; c_acc[i][j] = 0.f; g_acc[i][j] = 0.f; }

    for (int kc = 0; kc < KLEN; kc += CHK) {
        const int kb = k0 + kc;
        const float4 a0 = *(const float4*)(hn + (size_t)(row0 + lr) * HDIM + kb + lk);
        const float4 a1 = *(const float4*)(hn + (size_t)(row0 + 64 + lr) * HDIM + kb + lk);
        const float4 w0 = *(const float4*)(twp + (size_t)(col0 + lr) * HDIM + kb + lk);
        const float4 cc = *(const float4*)(cwp + (size_t)(kb + ck) * HDIM + col0 + co);
        const float4 gg = *(const float4*)(gwp + (size_t)(kb + ck) * HDIM + col0 + co);
        __syncthreads();
        hn_s[lk + 0][lr] = a0.x; hn_s[lk + 1][lr] = a0.y; hn_s[lk + 2][lr] = a0.z; hn_s[lk + 3][lr] = a0.w;
        hn_s[lk + 0][64 + lr] = a1.x; hn_s[lk + 1][64 + lr] = a1.y; hn_s[lk + 2][64 + lr] = a1.z; hn_s[lk + 3][64 + lr] = a1.w;
        wt_s[lk + 0][lr] = w0.x; wt_s[lk + 1][lr] = w0.y; wt_s[lk + 2][lr] = w0.z; wt_s[lk + 3][lr] = w0.w;
        *(float4*)&wc_s[ck][co] = cc;
        *(float4*)&wg_s[ck][co] = gg;
        __syncthreads();
#pragma unroll
        for (int k = 0; k < CHK; ++k) {
            const float4 h0 = *(const float4*)&hn_s[k][r0];
            const float4 h1 = *(const float4*)&hn_s[k][r0 + 4];
            const float4 wt = *(const float4*)&wt_s[k][c0];
            const float4 wc = *(const float4*)&wc_s[k][c0];
            const float4 wg = *(const float4*)&wg_s[k][c0];
            const float hf[8] = {h0.x, h0.y, h0.z, h0.w, h1.x, h1.y, h1.z, h1.w};
            const float wtf[4] = {wt.x, wt.y, wt.z, wt.w};
            const float wcf[4] = {wc.x, wc.y, wc.z, wc.w};
            const float wgf[4] = {wg.x, wg.y, wg.z, wg.w};
#pragma unroll
            for (int i = 0; i < 8; ++i) {
#pragma unroll
                for (int j = 0; j < 4; ++j) {
                    t_acc[i][j] = fmaxf(t_acc[i][j], hf[i] + wtf[j]);
                    c_acc[i][j] = fmaf(hf[i], wcf[j], c_acc[i][j]);
                    g_acc[i][j] = fmaf(hf[i], wgf[j], g_acc[i][j]);
                }
            }
        }
    }

    const size_t base = (size_t)blockIdx.z * BDIM * HDIM;
#pragma unroll
    for (int i = 0; i < 8; ++i) {
        const size_t off = base + (size_t)(row0 + r0 + i) * HDIM + col0 + c0;
        *(float4*)(p_trop + off) = make_float4(t_acc[i][0], t_acc[i][1], t_acc[i][2], t_acc[i][3]);
        *(float4*)(p_cls + off)  = make_float4(c_acc[i][0], c_acc[i][1], c_acc[i][2], c_acc[i][3]);
        *(float4*)(p_gate + off) = make_float4(g_acc[i][0], g_acc[i][1], g_acc[i][2], g_acc[i][3]);
    }
}

// ---------------------------------------------------------------------------
// Kernel 2 (per layer): reduce k-split partials, LF dual activation, gelu,
// gate, residual update of h, then LN for the NEXT layer (or final LN + head).
// One block per row.
// ---------------------------------------------------------------------------
__global__ __launch_bounds__(256) void combine_k(
    const float* __restrict__ p_trop, const float* __restrict__ p_cls, const float* __restrict__ p_gate,
    const float* __restrict__ trop_b,
    const float* __restrict__ amax, const float* __restrict__ bmax,
    const float* __restrict__ amin, const float* __restrict__ bmin,
    const float* __restrict__ alpha,
    const float* __restrict__ gate_b, const float* __restrict__ cls_b,
    float* __restrict__ h,
    const float* __restrict__ lng, const float* __restrict__ lnb,
    float* __restrict__ hn,
    const float* __restrict__ head_w, const float* __restrict__ head_b,
    float* __restrict__ out, const int is_last)
{
    const int b = blockIdx.x;
    const int t = threadIdx.x;
    __shared__ float rbuf[8];

    float hv[3];
    float s = 0.f, q = 0.f;
#pragma unroll
    for (int qq = 0; qq < 3; ++qq) {
        const int o = t + qq * 256;
        float tm = -1e30f, cs = 0.f, gs = 0.f;
#pragma unroll
        for (int k = 0; k < KS; ++k) {
            const size_t idx = (size_t)k * BDIM * HDIM + (size_t)b * HDIM + o;
            tm = fmaxf(tm, p_trop[idx]);
            cs += p_cls[idx];
            gs += p_gate[idx];
        }
        const float tv = tm + trop_b[o];
        float fmx = -1e30f, fmn = 1e30f;
#pragma unroll
        for (int p = 0; p < PDIM; ++p) {
            fmx = fmaxf(fmx, fmaf(tv, amax[o * PDIM + p], bmax[o * PDIM + p]));
            fmn = fminf(fmn, fmaf(tv, amin[o * PDIM + p], bmin[o * PDIM + p]));
        }
        const float a = sigmoidf_(alpha[o]);
        const float trop_out = a * fmx + (1.f - a) * fmn;
        const float cls_out = geluf_(cs + cls_b[o]);
        const float g = sigmoidf_(gs + gate_b[o]);
        const float val = h[(size_t)b * HDIM + o] + g * trop_out + (1.f - g) * cls_out;
        hv[qq] = val;
        h[(size_t)b * HDIM + o] = val;
        s += val; q += val * val;
    }

#pragma unroll
    for (int off = 32; off > 0; off >>= 1) { s += __shfl_down(s, off); q += __shfl_down(q, off); }
    const int wid = t >> 6, lane = t & 63;
    if (lane == 0) { rbuf[wid] = s; rbuf[4 + wid] = q; }
    __syncthreads();
    s = rbuf[0] + rbuf[1] + rbuf[2] + rbuf[3];
    q = rbuf[4] + rbuf[5] + rbuf[6] + rbuf[7];
    const float mu = s * (1.f / HDIM);
    const float var = q * (1.f / HDIM) - mu * mu;
    const float rsig = rsqrtf(var + 1e-5f);

    if (!is_last) {
#pragma unroll
        for (int qq = 0; qq < 3; ++qq) {
            const int o = t + qq * 256;
            hn[(size_t)b * HDIM + o] = (hv[qq] - mu) * rsig * lng[o] + lnb[o];
        }
    } else {
        float part = 0.f;
#pragma unroll
        for (int qq = 0; qq < 3; ++qq) {
            const int o = t + qq * 256;
            part += ((hv[qq] - mu) * rsig * lng[o] + lnb[o]) * head_w[o];
        }
#pragma unroll
        for (int off = 32; off > 0; off >>= 1) part += __shfl_down(part, off);
        __syncthreads();           // rbuf WAR protection
        if (lane == 0) rbuf[wid] = part;
        __syncthreads();
        if (t == 0) out[b] = rbuf[0] + rbuf[1] + rbuf[2] + rbuf[3] + head_b[0];
    }
}

// ---------------------------------------------------------------------------
extern "C" void kernel_launch(void* const* d_in, const int* in_sizes, int n_in,
                              void* d_out, int out_size, void* d_ws, size_t ws_size,
                              hipStream_t stream)
{
    const float* x       = (const float*)d_in[0];
    const float* w_in    = (const float*)d_in[1];
    const float* b_in    = (const float*)d_in[2];
    const float* ln_g    = (const float*)d_in[3];
    const float* ln_b    = (const float*)d_in[4];
    const float* trop_w  = (const float*)d_in[5];
    const float* trop_b  = (const float*)d_in[6];
    const float* lf_amax = (const float*)d_in[7];
    const float* lf_bmax = (const float*)d_in[8];
    const float* lf_amin = (const float*)d_in[9];
    const float* lf_bmin = (const float*)d_in[10];
    const float* lf_alpha= (const float*)d_in[11];
    const float* gate_w  = (const float*)d_in[12];
    const float* gate_b  = (const float*)d_in[13];
    const float* cls_w   = (const float*)d_in[14];
    const float* cls_b   = (const float*)d_in[15];
    const float* out_g   = (const float*)d_in[16];
    const float* out_b   = (const float*)d_in[17];
    const float* head_w  = (const float*)d_in[18];
    const float* head_b  = (const float*)d_in[19];
    float* out = (float*)d_out;

    const size_t NBH = (size_t)BDIM * HDIM;    // 196608
    float* ws = (float*)d_ws;
    float* h      = ws;                 // NBH
    float* hn     = ws + NBH;           // NBH
    float* p_trop = ws + 2 * NBH;       // KS*NBH
    float* p_cls  = p_trop + (size_t)KS * NBH;
    float* p_gate = p_cls + (size_t)KS * NBH;
    // total: (2 + 3*KS) * NBH * 4B ~= 29.9 MB

    input_ln_k<<<BDIM, 256, 0, stream>>>(x, w_in, b_in, ln_g, ln_b, h, hn);

    for (int l = 0; l < NLAYERS; ++l) {
        dim3 grid(HDIM / TC, BDIM / TR, KS);   // 12 x 2 x 12 = 288 blocks
        layer_mm_k<<<grid, 256, 0, stream>>>(
            hn,
            trop_w + (size_t)l * HDIM * HDIM,
            cls_w + (size_t)l * HDIM * HDIM,
            gate_w + (size_t)l * HDIM * HDIM,
            p_trop, p_cls, p_gate);

        const int is_last = (l == NLAYERS - 1);
        combine_k<<<BDIM, 256, 0, stream>>>(
            p_trop, p_cls, p_gate,
            trop_b + (size_t)l * HDIM,
            lf_amax + (size_t)l * HDIM * PDIM, lf_bmax + (size_t)l * HDIM * PDIM,
            lf_amin + (size_t)l * HDIM * PDIM, lf_bmin + (size_t)l * HDIM * PDIM,
            lf_alpha + (size_t)l * HDIM,
            gate_b + (size_t)l * HDIM, cls_b + (size_t)l * HDIM,
            h,
            is_last ? out_g : ln_g + (size_t)(l + 1) * HDIM,
            is_last ? out_b : ln_b + (size_t)(l + 1) * HDIM,
            hn, head_w, head_b, out, is_last);
    }
}